// Round 3
// baseline (6708.532 us; speedup 1.0000x reference)
//
#include <hip/hip_runtime.h>
#include <hip/hip_bf16.h>

// Problem constants
constexpr int kB  = 1024;
constexpr int kT  = 512;
constexpr int kF  = 32;
constexpr int kE  = 16;
constexpr int kH  = 128;
constexpr int kMB = 16;            // batches per block (MFMA M dimension)
constexpr int kGrid = kB / kMB;    // 64 blocks
constexpr int kTcc = 128;          // chunk length (ws budget: 1024*128*128*4B = 64 MiB)
constexpr int kNCh = kT / kTcc;    // 4 chunks

typedef __attribute__((ext_vector_type(8))) short s16x8;   // 8 bf16 (bit pattern)
typedef __attribute__((ext_vector_type(4))) float f32x4;

__device__ __forceinline__ float sigmf(float v){ return 1.0f/(1.0f+__expf(-v)); }
__device__ __forceinline__ float tanhfast(float v){ return 2.0f/(1.0f+__expf(-2.0f*v)) - 1.0f; }

__device__ __forceinline__ unsigned short bf16_rne(float f){
    unsigned u = __float_as_uint(f);
    return (unsigned short)((u + 0x7fffu + ((u>>16)&1u)) >> 16);
}
// split x into hi+lo bf16 (hi = rne(x), lo = rne(x - hi)): ~16-bit effective mantissa
__device__ __forceinline__ void split2(float x, unsigned short &hi, unsigned short &lo){
    hi = bf16_rne(x);
    lo = bf16_rne(x - __uint_as_float(((unsigned)hi)<<16));
}
__device__ __forceinline__ void loadB(const float* __restrict__ p, s16x8 &hi, s16x8 &lo){
#pragma unroll
    for (int j=0;j<8;j++){ unsigned short h,l; split2(p[j],h,l); hi[j]=(short)h; lo[j]=(short)l; }
}
#define MFMA(a,b,c) __builtin_amdgcn_mfma_f32_16x16x32_bf16(a,b,c,0,0,0)

// ---------------------------------------------------------------------------
// Layer-0 GRU chunk. 64 blocks x 768 threads (12 waves). Wave w owns gate-col
// tiles 2w,2w+1 (24 N-tiles of 16 over 3H=384). B-frags (W_hh0, W_ih0, emb-part)
// persistent in VGPRs as hi/lo bf16. A = h (16 batches x 128) from LDS; x/emb
// input transform fused (A = x_t 16x32 + const emb frag). Waves 0-7: r/z gates
// (gx+gh summed into one acc). Waves 8-11: n gates (separate gx/gh accs, since
// n = tanh(gx_n + r*gh_n)). Gates+state update on VALU (threads 0-511), x
// prefetch by threads 512-767. h written to h0seq as packed (hi<<16|lo) u32.
// ---------------------------------------------------------------------------
__global__ __launch_bounds__(768) void gru_l0_mfma(
    const float* __restrict__ x, const int* __restrict__ tick, const float* __restrict__ embed,
    const float* __restrict__ Wih, const float* __restrict__ Whh,
    const float* __restrict__ bih, const float* __restrict__ bhh,
    unsigned* __restrict__ h0seq, int chunk)
{
    __shared__ unsigned short hA_hi[16][136], hA_lo[16][136];   // h, A-frag layout (pad: 17x16B rows)
    __shared__ unsigned short xA_hi[2][16][40], xA_lo[2][16][40];
    __shared__ float hF[16][132];       // exact fp32 h
    __shared__ float rzS[16][260];      // r cols 0..127, z cols 128..255 (gx+gh+biases)
    __shared__ float ngx[16][132], ngh[16][132];

    const int tid = threadIdx.x;
    const int w = tid >> 6, l = tid & 63;
    const int lm = l & 15, lq = l >> 4;
    const int b0 = blockIdx.x * kMB;
    const bool isN = (w >= 8);

    // ---- persistent B fragments: B[k][n]: n=lane&15, k=quad*8+j
    s16x8 whhH[2][4], whhL[2][4], wi0H[2], wi0L[2], wieH[2], wieL[2];
#pragma unroll
    for (int tt=0; tt<2; tt++){
        const int row = (2*w+tt)*16 + lm;           // gate row 0..383
#pragma unroll
        for (int kt=0; kt<4; kt++)
            loadB(Whh + (size_t)row*kH + kt*32 + lq*8, whhH[tt][kt], whhL[tt][kt]);
        loadB(Wih + (size_t)row*48 + lq*8, wi0H[tt], wi0L[tt]);   // k-tile 0: x features 0..31
#pragma unroll
        for (int j=0;j<8;j++){                      // k-tile 1: cols 32..47 = emb, 48..63 = 0
            int k = 32 + lq*8 + j;
            float v = (k < 48) ? Wih[(size_t)row*48 + k] : 0.0f;
            unsigned short h,lo2; split2(v,h,lo2); wieH[tt][j]=(short)h; wieL[tt][j]=(short)lo2;
        }
    }
    // emb A-frag (constant over t): A[m=lm][k=32+lq*8+j]
    s16x8 eH, eL;
    {
        const int tk = tick[b0 + lm];
#pragma unroll
        for (int j=0;j<8;j++){
            int ke = lq*8 + j;
            float v = (ke < kE) ? embed[(size_t)tk*kE + ke] : 0.0f;
            unsigned short h,lo2; split2(v,h,lo2); eH[j]=(short)h; eL[j]=(short)lo2;
        }
    }
    float bs0=0,bs1=0,bx0=0,bx1=0,bh0=0,bh1=0;
    {
        const int c0 = 32*w + lm, c1 = c0 + 16;     // C-layout col = lane&15
        if (!isN){ bs0 = bih[c0]+bhh[c0]; bs1 = bih[c1]+bhh[c1]; }
        else     { bx0 = bih[c0]; bx1 = bih[c1]; bh0 = bhh[c0]; bh1 = bhh[c1]; }
    }

    // ---- init state (chunk 0: zeros; else carry from last step of prev chunk)
    if (chunk == 0){
        for (int i = tid; i < 16*136; i += 768){ ((unsigned short*)hA_hi)[i]=0; ((unsigned short*)hA_lo)[i]=0; }
        for (int i = tid; i < 16*132; i += 768) ((float*)hF)[i] = 0.0f;
    } else if (tid < 512){
        int m = tid>>5, i0 = (tid&31)*4;
        uint4 u = *(const uint4*)&h0seq[((size_t)(b0+m)*kTcc + (kTcc-1))*kH + i0];
        unsigned uu[4] = {u.x,u.y,u.z,u.w};
#pragma unroll
        for (int e=0;e<4;e++){
            unsigned short h = (unsigned short)(uu[e]>>16), lo2 = (unsigned short)(uu[e]&0xffffu);
            hA_hi[m][i0+e] = h; hA_lo[m][i0+e] = lo2;
            hF[m][i0+e] = __uint_as_float((unsigned)h<<16) + __uint_as_float((unsigned)lo2<<16);
        }
    }
    // stage x for tc=0
    if (tid >= 512){
        int q = tid - 512, m = q >> 4, f0 = (q & 15)*2;
        float2 xv = *(const float2*)&x[((size_t)(b0+m)*kT + (size_t)chunk*kTcc)*kF + f0];
        unsigned short ha,la,hb2,lb2; split2(xv.x,ha,la); split2(xv.y,hb2,lb2);
        xA_hi[0][m][f0]=ha; xA_hi[0][m][f0+1]=hb2;
        xA_lo[0][m][f0]=la; xA_lo[0][m][f0+1]=lb2;
    }
    __syncthreads();

    for (int tc = 0; tc < kTcc; tc++){
        const int buf = tc & 1;
        const int tg = chunk*kTcc + tc;
        // loader prefetch (issued early; latency hidden behind MFMA phase)
        float2 xpre = make_float2(0.f,0.f);
        const bool doPre = (tid >= 512) && (tc+1 < kTcc);
        int pm=0, pf=0;
        if (tid >= 512){ int q = tid-512; pm = q>>4; pf = (q&15)*2; }
        if (doPre) xpre = *(const float2*)&x[((size_t)(b0+pm)*kT + (tg+1))*kF + pf];

        // A fragments: A[m=lane&15][k=quad*8+j]
        s16x8 aH[4], aL[4];
#pragma unroll
        for (int kt=0; kt<4; kt++){
            aH[kt] = *(const s16x8*)&hA_hi[lm][kt*32 + lq*8];
            aL[kt] = *(const s16x8*)&hA_lo[lm][kt*32 + lq*8];
        }
        const s16x8 xH = *(const s16x8*)&xA_hi[buf][lm][lq*8];
        const s16x8 xL = *(const s16x8*)&xA_lo[buf][lm][lq*8];

        if (!isN){
            f32x4 a0 = {bs0,bs0,bs0,bs0}, a1 = {bs1,bs1,bs1,bs1};
#pragma unroll
            for (int kt=0; kt<4; kt++){
                a0 = MFMA(aH[kt], whhH[0][kt], a0); a0 = MFMA(aL[kt], whhH[0][kt], a0); a0 = MFMA(aH[kt], whhL[0][kt], a0);
                a1 = MFMA(aH[kt], whhH[1][kt], a1); a1 = MFMA(aL[kt], whhH[1][kt], a1); a1 = MFMA(aH[kt], whhL[1][kt], a1);
            }
            a0 = MFMA(xH, wi0H[0], a0); a0 = MFMA(xL, wi0H[0], a0); a0 = MFMA(xH, wi0L[0], a0);
            a0 = MFMA(eH, wieH[0], a0); a0 = MFMA(eL, wieH[0], a0); a0 = MFMA(eH, wieL[0], a0);
            a1 = MFMA(xH, wi0H[1], a1); a1 = MFMA(xL, wi0H[1], a1); a1 = MFMA(xH, wi0L[1], a1);
            a1 = MFMA(eH, wieH[1], a1); a1 = MFMA(eL, wieH[1], a1); a1 = MFMA(eH, wieL[1], a1);
#pragma unroll
            for (int q=0;q<4;q++){                   // C: col=lane&15, row=quad*4+reg
                rzS[lq*4+q][32*w + lm]      = a0[q];
                rzS[lq*4+q][32*w + 16 + lm] = a1[q];
            }
        } else {
            f32x4 g0 = {bx0,bx0,bx0,bx0}, g1 = {bx1,bx1,bx1,bx1};
            f32x4 h0v = {bh0,bh0,bh0,bh0}, h1v = {bh1,bh1,bh1,bh1};
#pragma unroll
            for (int kt=0; kt<4; kt++){
                h0v = MFMA(aH[kt], whhH[0][kt], h0v); h0v = MFMA(aL[kt], whhH[0][kt], h0v); h0v = MFMA(aH[kt], whhL[0][kt], h0v);
                h1v = MFMA(aH[kt], whhH[1][kt], h1v); h1v = MFMA(aL[kt], whhH[1][kt], h1v); h1v = MFMA(aH[kt], whhL[1][kt], h1v);
            }
            g0 = MFMA(xH, wi0H[0], g0); g0 = MFMA(xL, wi0H[0], g0); g0 = MFMA(xH, wi0L[0], g0);
            g0 = MFMA(eH, wieH[0], g0); g0 = MFMA(eL, wieH[0], g0); g0 = MFMA(eH, wieL[0], g0);
            g1 = MFMA(xH, wi0H[1], g1); g1 = MFMA(xL, wi0H[1], g1); g1 = MFMA(xH, wi0L[1], g1);
            g1 = MFMA(eH, wieH[1], g1); g1 = MFMA(eL, wieH[1], g1); g1 = MFMA(eH, wieL[1], g1);
            const int cb = 32*(w-8);
#pragma unroll
            for (int q=0;q<4;q++){
                ngx[lq*4+q][cb + lm]      = g0[q];
                ngx[lq*4+q][cb + 16 + lm] = g1[q];
                ngh[lq*4+q][cb + lm]      = h0v[q];
                ngh[lq*4+q][cb + 16 + lm] = h1v[q];
            }
        }
        __syncthreads();   // gh/rz complete

        if (tid < 512){
            const int m = tid>>5, i0 = (tid&31)*4;
            f32x4 rv = *(const f32x4*)&rzS[m][i0];
            f32x4 zv = *(const f32x4*)&rzS[m][128+i0];
            f32x4 nx = *(const f32x4*)&ngx[m][i0];
            f32x4 nh = *(const f32x4*)&ngh[m][i0];
            f32x4 ho = *(const f32x4*)&hF[m][i0];
            f32x4 hn;
            unsigned short hi4[4], lo4[4]; unsigned pk[4];
#pragma unroll
            for (int e=0;e<4;e++){
                float r = sigmf(rv[e]);
                float z = sigmf(zv[e]);
                float n = tanhfast(nx[e] + r*nh[e]);
                float h = (1.0f - z)*n + z*ho[e];
                hn[e] = h;
                split2(h, hi4[e], lo4[e]);
                pk[e] = ((unsigned)hi4[e]<<16) | lo4[e];
            }
            *(f32x4*)&hF[m][i0] = hn;
            *(ushort4*)&hA_hi[m][i0] = make_ushort4(hi4[0],hi4[1],hi4[2],hi4[3]);
            *(ushort4*)&hA_lo[m][i0] = make_ushort4(lo4[0],lo4[1],lo4[2],lo4[3]);
            *(uint4*)&h0seq[((size_t)(b0+m)*kTcc + tc)*kH + i0] = make_uint4(pk[0],pk[1],pk[2],pk[3]);
        } else if (doPre){
            unsigned short ha,la,hb2,lb2; split2(xpre.x,ha,la); split2(xpre.y,hb2,lb2);
            const int nb = buf^1;
            xA_hi[nb][pm][pf]=ha; xA_hi[nb][pm][pf+1]=hb2;
            xA_lo[nb][pm][pf]=la; xA_lo[nb][pm][pf+1]=lb2;
        }
        __syncthreads();   // hA/hF/xA ready for next step
    }
}

// ---------------------------------------------------------------------------
// Layer-1 GRU chunk + head. Same skeleton; A-operands: h1 (LDS) and h0_t
// (staged from packed h0seq by threads 512-767, double buffered). B-frags:
// W_ih1 + W_hh1 (32 frags, 128 VGPRs). Head runs on the last chunk.
// ---------------------------------------------------------------------------
__global__ __launch_bounds__(768) void gru_l1_mfma(
    const unsigned* __restrict__ h0seq,
    const float* __restrict__ Wih, const float* __restrict__ Whh,
    const float* __restrict__ bih, const float* __restrict__ bhh,
    const float* __restrict__ hw1, const float* __restrict__ hb1,
    const float* __restrict__ hw2, const float* __restrict__ hb2,
    float* __restrict__ h1state, float* __restrict__ out, int chunk)
{
    __shared__ unsigned short hA_hi[16][136], hA_lo[16][136];       // h1 state
    __shared__ unsigned short h0A_hi[2][16][136], h0A_lo[2][16][136]; // staged h0_t
    __shared__ float hF[16][132];
    __shared__ float rzS[16][260];
    __shared__ float ngx[16][132], ngh[16][132];

    const int tid = threadIdx.x;
    const int w = tid >> 6, l = tid & 63;
    const int lm = l & 15, lq = l >> 4;
    const int b0 = blockIdx.x * kMB;
    const bool isN = (w >= 8);

    s16x8 wihH[2][4], wihL[2][4], whhH[2][4], whhL[2][4];
#pragma unroll
    for (int tt=0; tt<2; tt++){
        const int row = (2*w+tt)*16 + lm;
#pragma unroll
        for (int kt=0; kt<4; kt++){
            loadB(Wih + (size_t)row*kH + kt*32 + lq*8, wihH[tt][kt], wihL[tt][kt]);
            loadB(Whh + (size_t)row*kH + kt*32 + lq*8, whhH[tt][kt], whhL[tt][kt]);
        }
    }
    float bs0=0,bs1=0,bx0=0,bx1=0,bh0=0,bh1=0;
    {
        const int c0 = 32*w + lm, c1 = c0 + 16;
        if (!isN){ bs0 = bih[c0]+bhh[c0]; bs1 = bih[c1]+bhh[c1]; }
        else     { bx0 = bih[c0]; bx1 = bih[c1]; bh0 = bhh[c0]; bh1 = bhh[c1]; }
    }

    if (chunk == 0){
        for (int i = tid; i < 16*136; i += 768){ ((unsigned short*)hA_hi)[i]=0; ((unsigned short*)hA_lo)[i]=0; }
        for (int i = tid; i < 16*132; i += 768) ((float*)hF)[i] = 0.0f;
    } else if (tid < 512){
        int m = tid>>5, i0 = (tid&31)*4;
        f32x4 hv = *(const f32x4*)&h1state[(size_t)(b0+m)*kH + i0];
#pragma unroll
        for (int e=0;e<4;e++){
            unsigned short h,lo2; split2(hv[e],h,lo2);
            hA_hi[m][i0+e]=h; hA_lo[m][i0+e]=lo2; hF[m][i0+e]=hv[e];
        }
    }
    // stage h0 for tc=0
    if (tid >= 512){
        int q = tid-512, m = q>>4, i0 = (q&15)*8;
        const unsigned* src = &h0seq[((size_t)(b0+m)*kTcc + 0)*kH + i0];
        uint4 u0 = *(const uint4*)src, u1 = *(const uint4*)(src+4);
        unsigned uu[8] = {u0.x,u0.y,u0.z,u0.w,u1.x,u1.y,u1.z,u1.w};
        s16x8 vh, vl;
#pragma unroll
        for (int e=0;e<8;e++){ vh[e]=(short)(uu[e]>>16); vl[e]=(short)(uu[e]&0xffffu); }
        *(s16x8*)&h0A_hi[0][m][i0] = vh;
        *(s16x8*)&h0A_lo[0][m][i0] = vl;
    }
    __syncthreads();

    for (int tc = 0; tc < kTcc; tc++){
        const int buf = tc & 1;
        uint4 u0 = make_uint4(0,0,0,0), u1 = make_uint4(0,0,0,0);
        const bool doPre = (tid >= 512) && (tc+1 < kTcc);
        int pm=0, pi=0;
        if (tid >= 512){ int q = tid-512; pm = q>>4; pi = (q&15)*8; }
        if (doPre){
            const unsigned* src = &h0seq[((size_t)(b0+pm)*kTcc + (tc+1))*kH + pi];
            u0 = *(const uint4*)src; u1 = *(const uint4*)(src+4);
        }

        s16x8 aH[4], aL[4], cH[4], cL[4];
#pragma unroll
        for (int kt=0; kt<4; kt++){
            aH[kt] = *(const s16x8*)&hA_hi[lm][kt*32 + lq*8];           // h1
            aL[kt] = *(const s16x8*)&hA_lo[lm][kt*32 + lq*8];
            cH[kt] = *(const s16x8*)&h0A_hi[buf][lm][kt*32 + lq*8];     // h0_t
            cL[kt] = *(const s16x8*)&h0A_lo[buf][lm][kt*32 + lq*8];
        }

        if (!isN){
            f32x4 a0 = {bs0,bs0,bs0,bs0}, a1 = {bs1,bs1,bs1,bs1};
#pragma unroll
            for (int kt=0; kt<4; kt++){
                a0 = MFMA(cH[kt], wihH[0][kt], a0); a0 = MFMA(cL[kt], wihH[0][kt], a0); a0 = MFMA(cH[kt], wihL[0][kt], a0);
                a0 = MFMA(aH[kt], whhH[0][kt], a0); a0 = MFMA(aL[kt], whhH[0][kt], a0); a0 = MFMA(aH[kt], whhL[0][kt], a0);
                a1 = MFMA(cH[kt], wihH[1][kt], a1); a1 = MFMA(cL[kt], wihH[1][kt], a1); a1 = MFMA(cH[kt], wihL[1][kt], a1);
                a1 = MFMA(aH[kt], whhH[1][kt], a1); a1 = MFMA(aL[kt], whhH[1][kt], a1); a1 = MFMA(aH[kt], whhL[1][kt], a1);
            }
#pragma unroll
            for (int q=0;q<4;q++){
                rzS[lq*4+q][32*w + lm]      = a0[q];
                rzS[lq*4+q][32*w + 16 + lm] = a1[q];
            }
        } else {
            f32x4 g0 = {bx0,bx0,bx0,bx0}, g1 = {bx1,bx1,bx1,bx1};
            f32x4 h0v = {bh0,bh0,bh0,bh0}, h1v = {bh1,bh1,bh1,bh1};
#pragma unroll
            for (int kt=0; kt<4; kt++){
                g0  = MFMA(cH[kt], wihH[0][kt], g0);  g0  = MFMA(cL[kt], wihH[0][kt], g0);  g0  = MFMA(cH[kt], wihL[0][kt], g0);
                h0v = MFMA(aH[kt], whhH[0][kt], h0v); h0v = MFMA(aL[kt], whhH[0][kt], h0v); h0v = MFMA(aH[kt], whhL[0][kt], h0v);
                g1  = MFMA(cH[kt], wihH[1][kt], g1);  g1  = MFMA(cL[kt], wihH[1][kt], g1);  g1  = MFMA(cH[kt], wihL[1][kt], g1);
                h1v = MFMA(aH[kt], whhH[1][kt], h1v); h1v = MFMA(aL[kt], whhH[1][kt], h1v); h1v = MFMA(aH[kt], whhL[1][kt], h1v);
            }
            const int cb = 32*(w-8);
#pragma unroll
            for (int q=0;q<4;q++){
                ngx[lq*4+q][cb + lm]      = g0[q];
                ngx[lq*4+q][cb + 16 + lm] = g1[q];
                ngh[lq*4+q][cb + lm]      = h0v[q];
                ngh[lq*4+q][cb + 16 + lm] = h1v[q];
            }
        }
        __syncthreads();

        if (tid < 512){
            const int m = tid>>5, i0 = (tid&31)*4;
            f32x4 rv = *(const f32x4*)&rzS[m][i0];
            f32x4 zv = *(const f32x4*)&rzS[m][128+i0];
            f32x4 nx = *(const f32x4*)&ngx[m][i0];
            f32x4 nh = *(const f32x4*)&ngh[m][i0];
            f32x4 ho = *(const f32x4*)&hF[m][i0];
            f32x4 hn;
            unsigned short hi4[4], lo4[4];
#pragma unroll
            for (int e=0;e<4;e++){
                float r = sigmf(rv[e]);
                float z = sigmf(zv[e]);
                float n = tanhfast(nx[e] + r*nh[e]);
                float h = (1.0f - z)*n + z*ho[e];
                hn[e] = h;
                split2(h, hi4[e], lo4[e]);
            }
            *(f32x4*)&hF[m][i0] = hn;
            *(ushort4*)&hA_hi[m][i0] = make_ushort4(hi4[0],hi4[1],hi4[2],hi4[3]);
            *(ushort4*)&hA_lo[m][i0] = make_ushort4(lo4[0],lo4[1],lo4[2],lo4[3]);
        } else if (doPre){
            unsigned uu[8] = {u0.x,u0.y,u0.z,u0.w,u1.x,u1.y,u1.z,u1.w};
            s16x8 vh, vl;
#pragma unroll
            for (int e=0;e<8;e++){ vh[e]=(short)(uu[e]>>16); vl[e]=(short)(uu[e]&0xffffu); }
            *(s16x8*)&h0A_hi[buf^1][pm][pi] = vh;
            *(s16x8*)&h0A_lo[buf^1][pm][pi] = vl;
        }
        __syncthreads();
    }

    // persist h1 for next chunk
    if (tid < 512){
        int m = tid>>5, i0 = (tid&31)*4;
        *(f32x4*)&h1state[(size_t)(b0+m)*kH + i0] = *(const f32x4*)&hF[m][i0];
    }

    if (chunk == kNCh-1){
        // head: hid = relu(h1 @ hw1^T + hb1); y = hid @ hw2^T + hb2
        if (tid < 512){
            const int m = tid>>5, i0 = (tid&31)*4;
#pragma unroll
            for (int e=0;e<4;e++){
                const float* wr = hw1 + (size_t)(i0+e)*kH;
                float s = hb1[i0+e];
                for (int k2=0;k2<kH;k2++) s = fmaf(wr[k2], hF[m][k2], s);
                rzS[m][i0+e] = fmaxf(s, 0.0f);
            }
        }
        __syncthreads();
        if (tid < kMB){
            float s = hb2[0];
            for (int k2=0;k2<kH;k2++) s = fmaf(rzS[tid][k2], hw2[k2], s);
            out[b0 + tid] = s;
        }
    }
}

extern "C" void kernel_launch(void* const* d_in, const int* in_sizes, int n_in,
                              void* d_out, int out_size, void* d_ws, size_t ws_size,
                              hipStream_t stream)
{
    const float* x     = (const float*)d_in[0];
    const int*   tick  = (const int*)d_in[1];
    const float* embed = (const float*)d_in[2];
    const float* Wih0  = (const float*)d_in[3];
    const float* Whh0  = (const float*)d_in[4];
    const float* bih0  = (const float*)d_in[5];
    const float* bhh0  = (const float*)d_in[6];
    const float* Wih1  = (const float*)d_in[7];
    const float* Whh1  = (const float*)d_in[8];
    const float* bih1  = (const float*)d_in[9];
    const float* bhh1  = (const float*)d_in[10];
    const float* hw1   = (const float*)d_in[11];
    const float* hb1   = (const float*)d_in[12];
    const float* hw2   = (const float*)d_in[13];
    const float* hb2   = (const float*)d_in[14];
    float* out = (float*)d_out;

    // ws: h0seq chunk (packed bf16 hi/lo u32) 64 MiB | h1 carry state 512 KiB
    unsigned* h0seq = (unsigned*)d_ws;
    float* h1state  = (float*)((char*)d_ws + (size_t)kB*kTcc*kH*sizeof(unsigned));

    for (int c = 0; c < kNCh; c++){
        gru_l0_mfma<<<kGrid, 768, 0, stream>>>(x, tick, embed, Wih0, Whh0, bih0, bhh0, h0seq, c);
        gru_l1_mfma<<<kGrid, 768, 0, stream>>>(h0seq, Wih1, Whh1, bih1, bhh1,
                                               hw1, hb1, hw2, hb2, h1state, out, c);
    }
}

// Round 4
// 2033.934 us; speedup vs baseline: 3.2983x; 3.2983x over previous
//
#include <hip/hip_runtime.h>
#include <hip/hip_bf16.h>
#include <hip/hip_fp16.h>

// Problem constants
constexpr int kB  = 1024;
constexpr int kT  = 512;
constexpr int kF  = 32;
constexpr int kE  = 16;
constexpr int kH  = 128;
constexpr int kG3 = 384;
constexpr int kMB = 16;            // batches per block (MFMA M)
constexpr int kNBlk = kB / kMB;    // 64 batch tiles
constexpr int kTc = 64;            // chunk length
constexpr int kNCh = kT / kTc;     // 8 chunks

typedef __attribute__((ext_vector_type(8))) short s16x8;   // 8 bf16 bit patterns
typedef __attribute__((ext_vector_type(4))) float f32x4;

#define MFMA(a,b,c) __builtin_amdgcn_mfma_f32_16x16x32_bf16(a,b,c,0,0,0)

__device__ __forceinline__ unsigned short bf16_rne(float f){
    unsigned u = __float_as_uint(f);
    return (unsigned short)((u + 0x7fffu + ((u>>16)&1u)) >> 16);
}
// x -> hi+lo bf16 pair (~16-bit effective mantissa for split MFMA)
__device__ __forceinline__ void split2(float x, unsigned short &hi, unsigned short &lo){
    hi = bf16_rne(x);
    lo = bf16_rne(x - __uint_as_float(((unsigned)hi)<<16));
}
__device__ __forceinline__ void loadB(const float* __restrict__ p, s16x8 &hi, s16x8 &lo){
#pragma unroll
    for (int j=0;j<8;j++){ unsigned short h,l; split2(p[j],h,l); hi[j]=(short)h; lo[j]=(short)l; }
}

// sigmoid via soft exp2 (full-rate fma poly) + hw v_rcp. Avoids v_exp:
// hw exp+rcp costs 768 quarter-rate cyc/step/SIMD, as big as the MFMA phase.
__device__ __forceinline__ float sigm_fast(float x){
    float y = x * -1.442695041f;                 // log2(e^-x)
    y = fminf(fmaxf(y, -125.f), 125.f);
    float k = rintf(y);
    float f = y - k;
    float p = 1.33335581e-3f;                    // Taylor of 2^f on [-0.5,0.5], err ~2e-6
    p = fmaf(p, f, 9.61812911e-3f);
    p = fmaf(p, f, 5.55041087e-2f);
    p = fmaf(p, f, 2.40226507e-1f);
    p = fmaf(p, f, 6.93147181e-1f);
    p = fmaf(p, f, 1.0f);
    float e = __int_as_float(__float_as_int(p) + (((int)k) << 23));
    return __builtin_amdgcn_rcpf(1.0f + e);      // v_rcp_f32: ~1 ulp
}
__device__ __forceinline__ float tanh_fast(float x){
    return fmaf(2.0f, sigm_fast(2.0f*x), -1.0f);
}
__device__ __forceinline__ float h2f(unsigned short u){
    __half_raw hr; hr.x = u; return __half2float((__half)hr);
}

// Fragment-ordered LDS h-planes: hf[kt][lq_group][slot(16)+pad][8 shorts].
// Reader lane (lm,lq) reads &hf[kt][lq][lm][0] as one b128 (lane-contiguous,
// stride-1-equivalent bank profile). Writer (updater thread owning (m,i0..i0+3))
// writes one short4 at [kt][ (i0>>3)&3 ][m][i0&7]. 17-slot pad breaks the
// 256B group stride that made writer lanes pile into 4 banks.
struct SmemL0 {
    short hfH[4][4][17][8], hfL[4][4][17][8];    // h state frags (hi/lo)
    short xfH[4][17][8],   xfL[4][17][8];        // x_t frags (K-tile 0 of xcat)
    float gp[4][16][132];                        // rs, zs, ngx, ngh planes
};
struct SmemL1 {
    short hfH[4][4][17][8], hfL[4][4][17][8];    // h1 state frags
    unsigned gxs[2][3072];                       // staged gx1_t (fp16, flat), dbuf
    float gp[3][16][132];                        // ghr, ghz, ghn planes
};
union SmemU { SmemL0 a; SmemL1 b; };

// ---------------------------------------------------------------------------
// Fused recurrent kernel. 128 blocks x 512 threads (8 waves, LB(512,2) ->
// 256-VGPR cap so weight frags stay register-resident).
//   blocks 0..63 : layer-0 GRU, chunk c   (skip if c==kNCh)
//   blocks 64..127: layer-1 GRU, chunk c-1 (skip if c==0) + head on last chunk
// Wave w owns gate cols 16w..16w+15 of each of r/z/n regions (3 N-tiles).
// Every thread is also an updater for h-elements (m=tid>>5, i0=(tid&31)*4).
// ---------------------------------------------------------------------------
__global__ __launch_bounds__(512, 2) void rnn_rec(
    const float* __restrict__ x, const int* __restrict__ tick, const float* __restrict__ embed,
    const float* __restrict__ Wih0, const float* __restrict__ Whh0,
    const float* __restrict__ bih0, const float* __restrict__ bhh0,
    const float* __restrict__ Whh1, const float* __restrict__ bhh1,
    const float* __restrict__ hw1, const float* __restrict__ hb1,
    const float* __restrict__ hw2, const float* __restrict__ hb2,
    unsigned* __restrict__ h0seq, const __half* __restrict__ gx1,
    float* __restrict__ h1state, float* __restrict__ out, int c)
{
    __shared__ SmemU sm;
    const int tid = threadIdx.x;
    const int w = tid>>6, l = tid&63, lm = l&15, lq = l>>4;
    const int m = tid>>5;              // updater batch row (0..15)
    const int i0 = (tid&31)*4;         // updater hidden slice
    const int ktU = i0>>5, lqU = (i0>>3)&3, j0 = i0&7;
    const bool isL0 = blockIdx.x < 64;
    const int mb = isL0 ? blockIdx.x : blockIdx.x - 64;
    const int b0 = mb * kMB;
    const int cols0 = 16*w + lm, cols1 = 128 + 16*w + lm, cols2 = 256 + 16*w + lm;

    if (isL0) {
        if (c >= kNCh) return;
        SmemL0 &S = sm.a;
        // ---- persistent weights (fully unrolled -> VGPR-resident)
        s16x8 wH[3][4], wL[3][4], xwH[3], xwL[3];
        {
            const int cls[3] = {cols0, cols1, cols2};
#pragma unroll
            for (int T=0; T<3; T++){
                const float* base = Whh0 + (size_t)cls[T]*kH;
#pragma unroll
                for (int kt=0; kt<4; kt++) loadB(base + kt*32 + lq*8, wH[T][kt], wL[T][kt]);
                loadB(Wih0 + (size_t)cls[T]*48 + lq*8, xwH[T], xwL[T]);
            }
        }
        // ---- acc inits: biases + (emb @ Wih0[:,32:48]) folded per (tile,row)
        float rIni[4], zIni[4], nxIni[4], nhIni;
        {
            int tkq[4];
#pragma unroll
            for (int q=0;q<4;q++) tkq[q] = tick[b0 + lq*4 + q];
            const int cls[3] = {cols0, cols1, cols2};
            float eb[3][4];
#pragma unroll
            for (int T=0; T<3; T++){
                const float* wr = Wih0 + (size_t)cls[T]*48 + 32;
#pragma unroll
                for (int q=0;q<4;q++){
                    const float* ep = embed + (size_t)tkq[q]*kE;
                    float s = 0.f;
#pragma unroll
                    for (int e=0;e<kE;e++) s = fmaf(ep[e], wr[e], s);
                    eb[T][q] = s;
                }
            }
            float br = bih0[cols0] + bhh0[cols0];
            float bz = bih0[cols1] + bhh0[cols1];
            float bn = bih0[cols2];
            nhIni = bhh0[cols2];
#pragma unroll
            for (int q=0;q<4;q++){ rIni[q]=br+eb[0][q]; zIni[q]=bz+eb[1][q]; nxIni[q]=bn+eb[2][q]; }
        }
        // ---- state init (chunk 0: zeros; else carry from h0seq last step)
        float hreg[4]; unsigned short hh[4], hl[4];
        if (c == 0){
#pragma unroll
            for (int e=0;e<4;e++){ hreg[e]=0.f; hh[e]=0; hl[e]=0; }
        } else {
            const unsigned* src = h0seq + ((size_t)(mb*kTc + (kTc-1))*4 + ktU)*512 + (lqU*16+m)*8 + j0;
            uint4 u = *(const uint4*)src;
            unsigned uu[4] = {u.x,u.y,u.z,u.w};
#pragma unroll
            for (int e=0;e<4;e++){
                hh[e]=(unsigned short)(uu[e]>>16); hl[e]=(unsigned short)uu[e];
                hreg[e]=__uint_as_float((unsigned)hh[e]<<16) + __uint_as_float((unsigned)hl[e]<<16);
            }
        }
        *(short4*)&S.hfH[ktU][lqU][m][j0] = make_short4((short)hh[0],(short)hh[1],(short)hh[2],(short)hh[3]);
        *(short4*)&S.hfL[ktU][lqU][m][j0] = make_short4((short)hl[0],(short)hl[1],(short)hl[2],(short)hl[3]);
        // ---- x element owned by this thread: (m, xk), staged 1 step ahead
        const int xk = tid & 31, xlq = xk>>3, xj = xk&7;
        const size_t xbase = (size_t)(b0+m)*kT*kF + xk;
        {
            float x0 = x[xbase + (size_t)(c*kTc)*kF];
            unsigned short a2,b2; split2(x0,a2,b2);
            S.xfH[xlq][m][xj]=(short)a2; S.xfL[xlq][m][xj]=(short)b2;
        }
        float xnext = x[xbase + (size_t)((c*kTc+1 < kT) ? c*kTc+1 : kT-1)*kF];
        __syncthreads();

        for (int tc=0; tc<kTc; tc++){
            // MFMA phase
            s16x8 aH[4], aL[4];
#pragma unroll
            for (int kt=0;kt<4;kt++){
                aH[kt]=*(const s16x8*)&S.hfH[kt][lq][lm][0];
                aL[kt]=*(const s16x8*)&S.hfL[kt][lq][lm][0];
            }
            s16x8 xH=*(const s16x8*)&S.xfH[lq][lm][0], xL=*(const s16x8*)&S.xfL[lq][lm][0];
            f32x4 aR ={rIni[0],rIni[1],rIni[2],rIni[3]};
            f32x4 aZ ={zIni[0],zIni[1],zIni[2],zIni[3]};
            f32x4 aNX={nxIni[0],nxIni[1],nxIni[2],nxIni[3]};
            f32x4 aNH={nhIni,nhIni,nhIni,nhIni};
#pragma unroll
            for (int kt=0;kt<4;kt++){
                aR =MFMA(aH[kt],wH[0][kt],aR);  aR =MFMA(aL[kt],wH[0][kt],aR);  aR =MFMA(aH[kt],wL[0][kt],aR);
                aZ =MFMA(aH[kt],wH[1][kt],aZ);  aZ =MFMA(aL[kt],wH[1][kt],aZ);  aZ =MFMA(aH[kt],wL[1][kt],aZ);
                aNH=MFMA(aH[kt],wH[2][kt],aNH); aNH=MFMA(aL[kt],wH[2][kt],aNH); aNH=MFMA(aH[kt],wL[2][kt],aNH);
            }
            aR =MFMA(xH,xwH[0],aR);  aR =MFMA(xL,xwH[0],aR);  aR =MFMA(xH,xwL[0],aR);
            aZ =MFMA(xH,xwH[1],aZ);  aZ =MFMA(xL,xwH[1],aZ);  aZ =MFMA(xH,xwL[1],aZ);
            aNX=MFMA(xH,xwH[2],aNX); aNX=MFMA(xL,xwH[2],aNX); aNX=MFMA(xH,xwL[2],aNX);
#pragma unroll
            for (int q=0;q<4;q++){
                S.gp[0][lq*4+q][16*w+lm]=aR[q];
                S.gp[1][lq*4+q][16*w+lm]=aZ[q];
                S.gp[2][lq*4+q][16*w+lm]=aNX[q];
                S.gp[3][lq*4+q][16*w+lm]=aNH[q];
            }
            __syncthreads();
            // update phase
            f32x4 rs=*(const f32x4*)&S.gp[0][m][i0];
            f32x4 zs=*(const f32x4*)&S.gp[1][m][i0];
            f32x4 nx=*(const f32x4*)&S.gp[2][m][i0];
            f32x4 nh=*(const f32x4*)&S.gp[3][m][i0];
            unsigned pk[4];
#pragma unroll
            for (int e=0;e<4;e++){
                float r = sigm_fast(rs[e]);
                float z = sigm_fast(zs[e]);
                float n = tanh_fast(fmaf(r, nh[e], nx[e]));
                float h = fmaf(z, hreg[e]-n, n);       // (1-z)n + z h
                hreg[e]=h;
                unsigned short h2,l2; split2(h,h2,l2);
                hh[e]=h2; hl[e]=l2; pk[e]=((unsigned)h2<<16)|l2;
            }
            *(short4*)&S.hfH[ktU][lqU][m][j0]=make_short4((short)hh[0],(short)hh[1],(short)hh[2],(short)hh[3]);
            *(short4*)&S.hfL[ktU][lqU][m][j0]=make_short4((short)hl[0],(short)hl[1],(short)hl[2],(short)hl[3]);
            *(uint4*)(h0seq + ((size_t)(mb*kTc + tc)*4 + ktU)*512 + (lqU*16+m)*8 + j0)
                = make_uint4(pk[0],pk[1],pk[2],pk[3]);
            { // stage x_{t+1}, prefetch x_{t+2}
                unsigned short a2,b2; split2(xnext,a2,b2);
                S.xfH[xlq][m][xj]=(short)a2; S.xfL[xlq][m][xj]=(short)b2;
                int tn = c*kTc + tc + 2; if (tn > kT-1) tn = kT-1;
                xnext = x[xbase + (size_t)tn*kF];
            }
            __syncthreads();
        }
    } else {
        if (c == 0) return;
        const int cc = c - 1;                          // chunk handled by l1
        SmemL1 &S = sm.b;
        s16x8 wH[3][4], wL[3][4];
        {
            const int cls[3] = {cols0, cols1, cols2};
#pragma unroll
            for (int T=0; T<3; T++){
                const float* base = Whh1 + (size_t)cls[T]*kH;
#pragma unroll
                for (int kt=0; kt<4; kt++) loadB(base + kt*32 + lq*8, wH[T][kt], wL[T][kt]);
            }
        }
        const float br=bhh1[cols0], bz=bhh1[cols1], bn=bhh1[cols2];
        float hreg[4]; unsigned short hh[4], hl[4];
        if (cc == 0){
#pragma unroll
            for (int e=0;e<4;e++){ hreg[e]=0.f; hh[e]=0; hl[e]=0; }
        } else {
            f32x4 hv = *(const f32x4*)&h1state[(size_t)(b0+m)*kH + i0];
#pragma unroll
            for (int e=0;e<4;e++){
                hreg[e]=hv[e];
                unsigned short h2,l2; split2(hv[e],h2,l2); hh[e]=h2; hl[e]=l2;
            }
        }
        *(short4*)&S.hfH[ktU][lqU][m][j0]=make_short4((short)hh[0],(short)hh[1],(short)hh[2],(short)hh[3]);
        *(short4*)&S.hfL[ktU][lqU][m][j0]=make_short4((short)hl[0],(short)hl[1],(short)hl[2],(short)hl[3]);
        // gx1 stream: 3072 u32 per (mb,t); stage t=0, prefetch t=1
        const unsigned* g32 = (const unsigned*)gx1;
        unsigned gpre[6];
#pragma unroll
        for (int j=0;j<6;j++) S.gxs[0][tid+512*j] = g32[(size_t)(mb*kTc + 0)*3072 + tid+512*j];
#pragma unroll
        for (int j=0;j<6;j++) gpre[j] = g32[(size_t)(mb*kTc + 1)*3072 + tid+512*j];
        __syncthreads();

        for (int tc=0; tc<kTc; tc++){
            const int buf = tc & 1;
            s16x8 aH[4], aL[4];
#pragma unroll
            for (int kt=0;kt<4;kt++){
                aH[kt]=*(const s16x8*)&S.hfH[kt][lq][lm][0];
                aL[kt]=*(const s16x8*)&S.hfL[kt][lq][lm][0];
            }
            f32x4 aR={br,br,br,br}, aZ={bz,bz,bz,bz}, aNH={bn,bn,bn,bn};
#pragma unroll
            for (int kt=0;kt<4;kt++){
                aR =MFMA(aH[kt],wH[0][kt],aR);  aR =MFMA(aL[kt],wH[0][kt],aR);  aR =MFMA(aH[kt],wL[0][kt],aR);
                aZ =MFMA(aH[kt],wH[1][kt],aZ);  aZ =MFMA(aL[kt],wH[1][kt],aZ);  aZ =MFMA(aH[kt],wL[1][kt],aZ);
                aNH=MFMA(aH[kt],wH[2][kt],aNH); aNH=MFMA(aL[kt],wH[2][kt],aNH); aNH=MFMA(aH[kt],wL[2][kt],aNH);
            }
#pragma unroll
            for (int q=0;q<4;q++){
                S.gp[0][lq*4+q][16*w+lm]=aR[q];
                S.gp[1][lq*4+q][16*w+lm]=aZ[q];
                S.gp[2][lq*4+q][16*w+lm]=aNH[q];
            }
            __syncthreads();
            f32x4 gr=*(const f32x4*)&S.gp[0][m][i0];
            f32x4 gz=*(const f32x4*)&S.gp[1][m][i0];
            f32x4 gn=*(const f32x4*)&S.gp[2][m][i0];
            const unsigned short* gxh = (const unsigned short*)&S.gxs[buf][0];
            ushort4 uR = *(const ushort4*)&gxh[m*kG3 + i0];
            ushort4 uZ = *(const ushort4*)&gxh[m*kG3 + 128 + i0];
            ushort4 uN = *(const ushort4*)&gxh[m*kG3 + 256 + i0];
            const unsigned short* pR=(const unsigned short*)&uR;
            const unsigned short* pZ=(const unsigned short*)&uZ;
            const unsigned short* pN=(const unsigned short*)&uN;
#pragma unroll
            for (int e=0;e<4;e++){
                float r = sigm_fast(h2f(pR[e]) + gr[e]);
                float z = sigm_fast(h2f(pZ[e]) + gz[e]);
                float n = tanh_fast(fmaf(r, gn[e], h2f(pN[e])));
                float h = fmaf(z, hreg[e]-n, n);
                hreg[e]=h;
                unsigned short h2,l2; split2(h,h2,l2); hh[e]=h2; hl[e]=l2;
            }
            *(short4*)&S.hfH[ktU][lqU][m][j0]=make_short4((short)hh[0],(short)hh[1],(short)hh[2],(short)hh[3]);
            *(short4*)&S.hfL[ktU][lqU][m][j0]=make_short4((short)hl[0],(short)hl[1],(short)hl[2],(short)hl[3]);
            { // stage gx_{t+1}, prefetch gx_{t+2}
#pragma unroll
                for (int j=0;j<6;j++) S.gxs[buf^1][tid+512*j] = gpre[j];
                int tn = tc + 2; if (tn > kTc-1) tn = kTc-1;
#pragma unroll
                for (int j=0;j<6;j++) gpre[j] = g32[(size_t)(mb*kTc + tn)*3072 + tid+512*j];
            }
            __syncthreads();
        }
        // persist h1 carry
        {
            f32x4 hv = {hreg[0],hreg[1],hreg[2],hreg[3]};
            *(f32x4*)&h1state[(size_t)(b0+m)*kH + i0] = hv;
        }
        if (cc == kNCh-1){
            // head: hid = relu(h1 @ hw1^T + hb1); y = hid @ hw2^T + hb2
            f32x4 hv = {hreg[0],hreg[1],hreg[2],hreg[3]};
            *(f32x4*)&S.gp[0][m][i0] = hv;
            __syncthreads();
#pragma unroll
            for (int e=0;e<4;e++){
                const float* wr = hw1 + (size_t)(i0+e)*kH;
                float s = hb1[i0+e];
                for (int k2=0;k2<kH;k2++) s = fmaf(wr[k2], S.gp[0][m][k2], s);
                S.gp[1][m][i0+e] = fmaxf(s, 0.f);
            }
            __syncthreads();
            if (tid < kMB){
                float s = hb2[0];
                for (int k2=0;k2<kH;k2++) s = fmaf(S.gp[1][tid][k2], hw2[k2], s);
                out[b0 + tid] = s;
            }
        }
    }
}

// ---------------------------------------------------------------------------
// gx1 = h0_chunk @ Wih1^T + bih1 (non-recurrent, full machine).
// 512 blocks (64 mtiles x 8 t-groups) x 512 threads. Reads packed hi/lo h0seq
// in fragment order (fully coalesced), writes fp16 gx1.
// ---------------------------------------------------------------------------
__global__ __launch_bounds__(512, 2) void gx1_gemm(
    const unsigned* __restrict__ h0seq, const float* __restrict__ Wih1,
    const float* __restrict__ bih1, __half* __restrict__ gx1)
{
    const int tid=threadIdx.x, w=tid>>6, l=tid&63, lm=l&15, lq=l>>4;
    const int mb = blockIdx.x >> 3, tg = blockIdx.x & 7;
    s16x8 wH[3][4], wL[3][4];
    float bI[3]; int cols[3];
#pragma unroll
    for (int j=0;j<3;j++){
        cols[j] = (3*w+j)*16 + lm;
        const float* base = Wih1 + (size_t)cols[j]*kH;
#pragma unroll
        for (int kt=0;kt<4;kt++) loadB(base + kt*32 + lq*8, wH[j][kt], wL[j][kt]);
        bI[j] = bih1[cols[j]];
    }
    for (int tt=0; tt<8; tt++){
        const int t = tg*8 + tt;
        s16x8 aH[4], aL[4];
#pragma unroll
        for (int kt=0;kt<4;kt++){
            const unsigned* src = h0seq + ((size_t)(mb*kTc + t)*4 + kt)*512 + (lq*16+lm)*8;
            uint4 u0=*(const uint4*)src, u1=*(const uint4*)(src+4);
            unsigned uu[8]={u0.x,u0.y,u0.z,u0.w,u1.x,u1.y,u1.z,u1.w};
            s16x8 vh, vl;
#pragma unroll
            for (int e=0;e<8;e++){ vh[e]=(short)(uu[e]>>16); vl[e]=(short)uu[e]; }
            aH[kt]=vh; aL[kt]=vl;
        }
#pragma unroll
        for (int j=0;j<3;j++){
            f32x4 acc={bI[j],bI[j],bI[j],bI[j]};
#pragma unroll
            for (int kt=0;kt<4;kt++){
                acc=MFMA(aH[kt],wH[j][kt],acc);
                acc=MFMA(aL[kt],wH[j][kt],acc);
                acc=MFMA(aH[kt],wL[j][kt],acc);
            }
#pragma unroll
            for (int q=0;q<4;q++)
                gx1[((size_t)(mb*kTc + t)*16 + lq*4+q)*kG3 + cols[j]] = __float2half(acc[q]);
        }
    }
}

extern "C" void kernel_launch(void* const* d_in, const int* in_sizes, int n_in,
                              void* d_out, int out_size, void* d_ws, size_t ws_size,
                              hipStream_t stream)
{
    const float* x     = (const float*)d_in[0];
    const int*   tick  = (const int*)d_in[1];
    const float* embed = (const float*)d_in[2];
    const float* Wih0  = (const float*)d_in[3];
    const float* Whh0  = (const float*)d_in[4];
    const float* bih0  = (const float*)d_in[5];
    const float* bhh0  = (const float*)d_in[6];
    const float* Wih1  = (const float*)d_in[7];
    const float* Whh1  = (const float*)d_in[8];
    const float* bih1  = (const float*)d_in[9];
    const float* bhh1  = (const float*)d_in[10];
    const float* hw1   = (const float*)d_in[11];
    const float* hb1   = (const float*)d_in[12];
    const float* hw2   = (const float*)d_in[13];
    const float* hb2   = (const float*)d_in[14];
    float* out = (float*)d_out;

    // ws: h0seq (packed bf16 hi/lo, frag-ordered) 32MB | gx1 fp16 48MB | h1 carry 0.5MB
    unsigned* h0seq = (unsigned*)d_ws;
    __half*   gx1   = (__half*)((char*)d_ws + (size_t)kNBlk*kTc*4*512*sizeof(unsigned));
    float*  h1state = (float*)((char*)gx1 + (size_t)kB*kTc*kG3*sizeof(__half));

    // software pipeline: R(c) runs l0(chunk c) + l1(chunk c-1) concurrently on
    // 128 blocks; G(c) then produces gx1(chunk c) for the next R.
    for (int c=0; c<=kNCh; c++){
        rnn_rec<<<128, 512, 0, stream>>>(x, tick, embed, Wih0, Whh0, bih0, bhh0,
                                         Whh1, bhh1, hw1, hb1, hw2, hb2,
                                         h0seq, gx1, h1state, out, c);
        if (c < kNCh)
            gx1_gemm<<<512, 512, 0, stream>>>(h0seq, Wih1, bih1, gx1);
    }
}

// Round 5
// 1363.445 us; speedup vs baseline: 4.9203x; 1.4918x over previous
//
#include <hip/hip_runtime.h>

// Problem constants
constexpr int kB  = 1024;
constexpr int kT  = 512;
constexpr int kF  = 32;
constexpr int kE  = 16;
constexpr int kH  = 128;
constexpr int kG3 = 384;
constexpr int kMB = 16;            // batches per block (MFMA M)
constexpr int kTc = 32;            // chunk length
constexpr int kNCh = kT / kTc;     // 16 chunks
constexpr size_t kH0Str = (size_t)kB * kTc * kH;    // u32 elems per h0 chunk buffer (16 MB)
constexpr size_t kGxStr = (size_t)kB * kTc * kG3;   // f16 elems per gx chunk buffer (24 MB)

typedef __attribute__((ext_vector_type(8))) _Float16 f16x8;
typedef __attribute__((ext_vector_type(4))) _Float16 f16x4;
typedef __attribute__((ext_vector_type(4))) float    f32x4;

#define MFMA16(a,b,c) __builtin_amdgcn_mfma_f32_16x16x32_f16(a,b,c,0,0,0)

// activations on hw transcendentals: v_exp_f32 (=2^x) + v_rcp_f32, 4 inst total
__device__ __forceinline__ float sigm_hw(float x){
    float e = exp2f(-1.442695041f * x);
    return __builtin_amdgcn_rcpf(1.0f + e);
}
__device__ __forceinline__ float tanh_hw(float x){
    float e = exp2f(-2.885390082f * x);
    return fmaf(2.0f, __builtin_amdgcn_rcpf(1.0f + e), -1.0f);
}
// float -> fp16 hi/lo pair (~22-bit effective mantissa for 2-product MFMA)
__device__ __forceinline__ void splitF(float v, _Float16 &hi, _Float16 &lo){
    hi = (_Float16)v;
    lo = (_Float16)(v - (float)hi);
}
__device__ __forceinline__ f16x8 loadW8(const float* __restrict__ p){
    f16x8 r;
#pragma unroll
    for (int j=0;j<8;j++) r[j] = (_Float16)p[j];
    return r;
}
__device__ __forceinline__ unsigned short f2u(_Float16 h){ return __builtin_bit_cast(unsigned short, h); }
__device__ __forceinline__ _Float16 u2f(unsigned short u){ return __builtin_bit_cast(_Float16, u); }

// LDS layouts. h fragments stored fragment-ordered: [kt][lq][slot17][8 f16];
// reader lane l=lq*16+lm reads [kt][lq][lm][0..7] as one b128 (lane-contiguous
// within each 16-lane phase -> conflict-free); 17-slot pad makes the updater's
// 8B writes land 2-way (free) instead of 16-way.
struct SmemL0 {
    alignas(16) _Float16 hfH[4][4][17][8];
    alignas(16) _Float16 hfL[4][4][17][8];
    alignas(16) _Float16 xfH[4][17][8];
    alignas(16) _Float16 xfL[4][17][8];
    alignas(16) float gp[4][16][132];     // r, z, nx, nh planes (C-layout)
};
struct SmemL1 {
    alignas(16) _Float16 hfH[4][4][17][8];
    alignas(16) _Float16 hfL[4][4][17][8];
    alignas(16) unsigned gxs[2][3072];    // staged gx1_t (fp16 pairs), dbuf
    alignas(16) float gp[3][16][132];     // ghr, ghz, ghn planes
};
union SmemU { SmemL0 a; SmemL1 b; };

// ---------------------------------------------------------------------------
// One launch = 3 pipeline stages on 256 blocks x 512 threads:
//   blocks   0..63 : layer-0 GRU, chunk c      (skip if c>=kNCh)
//   blocks 64..191 : gx1 = h0(c-1) @ Wih1^T+b  (skip unless 0<=c-1<kNCh)
//   blocks 192..255: layer-1 GRU, chunk c-2    (skip if c<2), head on last
// amdgpu_waves_per_eu(2,2): pin 1 block/CU -> 256-VGPR budget so the weight
// fragments stay register-resident (launch_bounds(512,2) alone let the
// backend target 4 waves/EU = 128 regs and rematerialize weights per step).
// ---------------------------------------------------------------------------
__attribute__((amdgpu_waves_per_eu(2, 2)))
__global__ void __launch_bounds__(512) rnn_fused(
    const float* __restrict__ x, const int* __restrict__ tick,
    const float* __restrict__ embed,
    const float* __restrict__ Wih0, const float* __restrict__ Whh0,
    const float* __restrict__ bih0, const float* __restrict__ bhh0,
    const float* __restrict__ Wih1, const float* __restrict__ bih1,
    const float* __restrict__ Whh1, const float* __restrict__ bhh1,
    const float* __restrict__ hw1, const float* __restrict__ hb1,
    const float* __restrict__ hw2, const float* __restrict__ hb2,
    unsigned* __restrict__ h0seq, _Float16* __restrict__ gx1,
    float* __restrict__ h1state, float* __restrict__ out, int c)
{
    __shared__ SmemU sm;
    const int tid = threadIdx.x;
    const int w = tid >> 6, l = tid & 63, lm = l & 15, lq = l >> 4;
    const int m  = tid >> 5;               // updater batch row
    const int i0 = (tid & 31) * 4;         // updater hidden slice
    const int ktU = i0 >> 5, lqU = (i0 >> 3) & 3, j0 = i0 & 7;
    const int cls0 = 16*w + lm, cls1 = 128 + cls0, cls2 = 256 + cls0;

    if (blockIdx.x < 64) {
        // ================= layer-0 recurrence, chunk c =================
        if (c >= kNCh) return;
        SmemL0 &S = sm.a;
        const int mb = blockIdx.x, b0 = mb * kMB;
        unsigned* h0w = h0seq + (size_t)(c & 1) * kH0Str;

        // persistent weights (fp16, fully unrolled -> SSA -> VGPRs)
        f16x8 wv[3][4], xw[3];
        {
            const int cls[3] = {cls0, cls1, cls2};
#pragma unroll
            for (int T=0; T<3; T++){
#pragma unroll
                for (int kt=0; kt<4; kt++)
                    wv[T][kt] = loadW8(Whh0 + (size_t)cls[T]*kH + kt*32 + lq*8);
                xw[T] = loadW8(Wih0 + (size_t)cls[T]*48 + lq*8);
            }
        }
        // acc inits: biases + (emb @ Wih0[:,32:48]) folded, exact fp32
        float rIni[4], zIni[4], nxIni[4], nhIni;
        {
            int tkq[4];
#pragma unroll
            for (int q=0;q<4;q++) tkq[q] = tick[b0 + lq*4 + q];
            const int cls[3] = {cls0, cls1, cls2};
            float eb[3][4];
#pragma unroll
            for (int T=0; T<3; T++){
                const float* wr = Wih0 + (size_t)cls[T]*48 + 32;
#pragma unroll
                for (int q=0;q<4;q++){
                    const float* ep = embed + (size_t)tkq[q]*kE;
                    float s = 0.f;
#pragma unroll
                    for (int e=0;e<kE;e++) s = fmaf(ep[e], wr[e], s);
                    eb[T][q] = s;
                }
            }
            float br = bih0[cls0] + bhh0[cls0];
            float bz = bih0[cls1] + bhh0[cls1];
            float bn = bih0[cls2];
            nhIni = bhh0[cls2];
#pragma unroll
            for (int q=0;q<4;q++){ rIni[q]=br+eb[0][q]; zIni[q]=bz+eb[1][q]; nxIni[q]=bn+eb[2][q]; }
        }
        // state init
        float hreg[4]; _Float16 hh[4], hl[4];
        if (c == 0){
#pragma unroll
            for (int e=0;e<4;e++){ hreg[e]=0.f; hh[e]=(_Float16)0.f; hl[e]=(_Float16)0.f; }
        } else {
            const unsigned* h0p = h0seq + (size_t)((c-1) & 1) * kH0Str;
            uint4 u = *(const uint4*)(h0p + ((size_t)(mb*kTc + (kTc-1))*4 + ktU)*512 + (lqU*16+m)*8 + j0);
            unsigned uu[4] = {u.x,u.y,u.z,u.w};
#pragma unroll
            for (int e=0;e<4;e++){
                hh[e]=u2f((unsigned short)(uu[e]>>16)); hl[e]=u2f((unsigned short)uu[e]);
                hreg[e]=(float)hh[e] + (float)hl[e];
            }
        }
        *(f16x4*)&S.hfH[ktU][lqU][m][j0] = (f16x4){hh[0],hh[1],hh[2],hh[3]};
        *(f16x4*)&S.hfL[ktU][lqU][m][j0] = (f16x4){hl[0],hl[1],hl[2],hl[3]};
        // x ownership: (m, xk); stage t=0, prefetch t=1
        const int xk = tid & 31, xlq = xk >> 3, xj = xk & 7;
        const size_t xbase = (size_t)(b0+m)*kT*kF + xk;
        {
            _Float16 a2,b2; splitF(x[xbase + (size_t)(c*kTc)*kF], a2, b2);
            S.xfH[xlq][m][xj]=a2; S.xfL[xlq][m][xj]=b2;
        }
        float xnext = x[xbase + (size_t)((c*kTc+1 < kT) ? c*kTc+1 : kT-1)*kF];
        __syncthreads();

        for (int tc=0; tc<kTc; tc++){
            // ---- MFMA phase (30 MFMA / wave / step)
            f16x8 aH[4], aL[4];
#pragma unroll
            for (int kt=0;kt<4;kt++){
                aH[kt]=*(const f16x8*)&S.hfH[kt][lq][lm][0];
                aL[kt]=*(const f16x8*)&S.hfL[kt][lq][lm][0];
            }
            f16x8 xH=*(const f16x8*)&S.xfH[lq][lm][0], xL=*(const f16x8*)&S.xfL[lq][lm][0];
            f32x4 aR ={rIni[0],rIni[1],rIni[2],rIni[3]};
            f32x4 aZ ={zIni[0],zIni[1],zIni[2],zIni[3]};
            f32x4 aNX={nxIni[0],nxIni[1],nxIni[2],nxIni[3]};
            f32x4 aNH={nhIni,nhIni,nhIni,nhIni};
#pragma unroll
            for (int kt=0;kt<4;kt++){
                aR =MFMA16(aH[kt],wv[0][kt],aR);  aR =MFMA16(aL[kt],wv[0][kt],aR);
                aZ =MFMA16(aH[kt],wv[1][kt],aZ);  aZ =MFMA16(aL[kt],wv[1][kt],aZ);
                aNH=MFMA16(aH[kt],wv[2][kt],aNH); aNH=MFMA16(aL[kt],wv[2][kt],aNH);
            }
            aR =MFMA16(xH,xw[0],aR);  aR =MFMA16(xL,xw[0],aR);
            aZ =MFMA16(xH,xw[1],aZ);  aZ =MFMA16(xL,xw[1],aZ);
            aNX=MFMA16(xH,xw[2],aNX); aNX=MFMA16(xL,xw[2],aNX);
#pragma unroll
            for (int q=0;q<4;q++){                 // C: col=lane&15, row=lq*4+q
                S.gp[0][lq*4+q][cls0]=aR[q];
                S.gp[1][lq*4+q][cls0]=aZ[q];
                S.gp[2][lq*4+q][cls0]=aNX[q];
                S.gp[3][lq*4+q][cls0]=aNH[q];
            }
            __syncthreads();
            // ---- update phase
            f32x4 rs=*(const f32x4*)&S.gp[0][m][i0];
            f32x4 zs=*(const f32x4*)&S.gp[1][m][i0];
            f32x4 nx=*(const f32x4*)&S.gp[2][m][i0];
            f32x4 nh=*(const f32x4*)&S.gp[3][m][i0];
            unsigned pk[4];
#pragma unroll
            for (int e=0;e<4;e++){
                float r = sigm_hw(rs[e]);
                float z = sigm_hw(zs[e]);
                float n = tanh_hw(fmaf(r, nh[e], nx[e]));
                float h = fmaf(z, hreg[e]-n, n);
                hreg[e]=h;
                splitF(h, hh[e], hl[e]);
                pk[e] = ((unsigned)f2u(hh[e])<<16) | f2u(hl[e]);
            }
            *(f16x4*)&S.hfH[ktU][lqU][m][j0] = (f16x4){hh[0],hh[1],hh[2],hh[3]};
            *(f16x4*)&S.hfL[ktU][lqU][m][j0] = (f16x4){hl[0],hl[1],hl[2],hl[3]};
            *(uint4*)(h0w + ((size_t)(mb*kTc + tc)*4 + ktU)*512 + (lqU*16+m)*8 + j0)
                = make_uint4(pk[0],pk[1],pk[2],pk[3]);
            { // stage x_{t+1}, prefetch x_{t+2}
                _Float16 a2,b2; splitF(xnext,a2,b2);
                S.xfH[xlq][m][xj]=a2; S.xfL[xlq][m][xj]=b2;
                int tn = c*kTc + tc + 2; if (tn > kT-1) tn = kT-1;
                xnext = x[xbase + (size_t)tn*kF];
            }
            __syncthreads();
        }
    } else if (blockIdx.x < 192) {
        // ============ gx1 GEMM for chunk g=c-1 (non-recurrent) ============
        const int g = c - 1;
        if (g < 0 || g >= kNCh) return;
        const int bid = blockIdx.x - 64;
        const int mb = bid >> 1, t0 = (bid & 1) * (kTc/2);
        const unsigned* h0r = h0seq + (size_t)(g & 1) * kH0Str;
        _Float16* gxw = gx1 + (size_t)(g & 1) * kGxStr;
        f16x8 wv[3][4]; float bI[3];
        const int cls[3] = {cls0, cls1, cls2};
#pragma unroll
        for (int T=0; T<3; T++){
#pragma unroll
            for (int kt=0; kt<4; kt++)
                wv[T][kt] = loadW8(Wih1 + (size_t)cls[T]*kH + kt*32 + lq*8);
            bI[T] = bih1[cls[T]];
        }
        for (int tt=0; tt<kTc/2; tt++){
            const int t = t0 + tt;
            f16x8 aH[4], aL[4];
#pragma unroll
            for (int kt=0;kt<4;kt++){
                const unsigned* src = h0r + ((size_t)(mb*kTc + t)*4 + kt)*512 + (size_t)l*8;
                uint4 u0=*(const uint4*)src, u1=*(const uint4*)(src+4);
                unsigned uu[8]={u0.x,u0.y,u0.z,u0.w,u1.x,u1.y,u1.z,u1.w};
                f16x8 vh, vl;
#pragma unroll
                for (int e=0;e<8;e++){ vh[e]=u2f((unsigned short)(uu[e]>>16)); vl[e]=u2f((unsigned short)uu[e]); }
                aH[kt]=vh; aL[kt]=vl;
            }
#pragma unroll
            for (int T=0; T<3; T++){
                f32x4 acc={bI[T],bI[T],bI[T],bI[T]};
#pragma unroll
                for (int kt=0;kt<4;kt++){
                    acc=MFMA16(aH[kt],wv[T][kt],acc);
                    acc=MFMA16(aL[kt],wv[T][kt],acc);
                }
#pragma unroll
                for (int q=0;q<4;q++)
                    gxw[((size_t)(mb*kTc + t)*16 + lq*4+q)*kG3 + cls[T]] = (_Float16)acc[q];
            }
        }
    } else {
        // ================= layer-1 recurrence, chunk e=c-2 =================
        const int e0 = c - 2;
        if (e0 < 0 || e0 >= kNCh) return;
        SmemL1 &S = sm.b;
        const int mb = blockIdx.x - 192, b0 = mb * kMB;
        const unsigned* g32 = (const unsigned*)(gx1 + (size_t)(e0 & 1) * kGxStr);

        f16x8 wv[3][4];
        {
            const int cls[3] = {cls0, cls1, cls2};
#pragma unroll
            for (int T=0; T<3; T++)
#pragma unroll
                for (int kt=0; kt<4; kt++)
                    wv[T][kt] = loadW8(Whh1 + (size_t)cls[T]*kH + kt*32 + lq*8);
        }
        const float br=bhh1[cls0], bz=bhh1[cls1], bn=bhh1[cls2];
        float hreg[4]; _Float16 hh[4], hl[4];
        if (e0 == 0){
#pragma unroll
            for (int e=0;e<4;e++){ hreg[e]=0.f; hh[e]=(_Float16)0.f; hl[e]=(_Float16)0.f; }
        } else {
            f32x4 hv = *(const f32x4*)&h1state[(size_t)(b0+m)*kH + i0];
#pragma unroll
            for (int e=0;e<4;e++){ hreg[e]=hv[e]; splitF(hv[e], hh[e], hl[e]); }
        }
        *(f16x4*)&S.hfH[ktU][lqU][m][j0] = (f16x4){hh[0],hh[1],hh[2],hh[3]};
        *(f16x4*)&S.hfL[ktU][lqU][m][j0] = (f16x4){hl[0],hl[1],hl[2],hl[3]};
        // stage gx_t=0, prefetch t=1 (3072 u32/step, coalesced)
        unsigned gpre[6];
#pragma unroll
        for (int j=0;j<6;j++) S.gxs[0][tid+512*j] = g32[(size_t)(mb*kTc + 0)*3072 + tid+512*j];
#pragma unroll
        for (int j=0;j<6;j++) gpre[j] = g32[(size_t)(mb*kTc + 1)*3072 + tid+512*j];
        __syncthreads();

        for (int tc=0; tc<kTc; tc++){
            const int buf = tc & 1;
            f16x8 aH[4], aL[4];
#pragma unroll
            for (int kt=0;kt<4;kt++){
                aH[kt]=*(const f16x8*)&S.hfH[kt][lq][lm][0];
                aL[kt]=*(const f16x8*)&S.hfL[kt][lq][lm][0];
            }
            f32x4 aR={br,br,br,br}, aZ={bz,bz,bz,bz}, aNH={bn,bn,bn,bn};
#pragma unroll
            for (int kt=0;kt<4;kt++){
                aR =MFMA16(aH[kt],wv[0][kt],aR);  aR =MFMA16(aL[kt],wv[0][kt],aR);
                aZ =MFMA16(aH[kt],wv[1][kt],aZ);  aZ =MFMA16(aL[kt],wv[1][kt],aZ);
                aNH=MFMA16(aH[kt],wv[2][kt],aNH); aNH=MFMA16(aL[kt],wv[2][kt],aNH);
            }
#pragma unroll
            for (int q=0;q<4;q++){
                S.gp[0][lq*4+q][cls0]=aR[q];
                S.gp[1][lq*4+q][cls0]=aZ[q];
                S.gp[2][lq*4+q][cls0]=aNH[q];
            }
            __syncthreads();
            f32x4 gr=*(const f32x4*)&S.gp[0][m][i0];
            f32x4 gz=*(const f32x4*)&S.gp[1][m][i0];
            f32x4 gn=*(const f32x4*)&S.gp[2][m][i0];
            const unsigned short* gxh = (const unsigned short*)&S.gxs[buf][0];
            ushort4 uR = *(const ushort4*)&gxh[m*kG3 + i0];
            ushort4 uZ = *(const ushort4*)&gxh[m*kG3 + 128 + i0];
            ushort4 uN = *(const ushort4*)&gxh[m*kG3 + 256 + i0];
            const unsigned short* pR=(const unsigned short*)&uR;
            const unsigned short* pZ=(const unsigned short*)&uZ;
            const unsigned short* pN=(const unsigned short*)&uN;
#pragma unroll
            for (int e=0;e<4;e++){
                float r = sigm_hw((float)u2f(pR[e]) + gr[e]);
                float z = sigm_hw((float)u2f(pZ[e]) + gz[e]);
                float n = tanh_hw(fmaf(r, gn[e], (float)u2f(pN[e])));
                float h = fmaf(z, hreg[e]-n, n);
                hreg[e]=h;
                splitF(h, hh[e], hl[e]);
            }
            *(f16x4*)&S.hfH[ktU][lqU][m][j0] = (f16x4){hh[0],hh[1],hh[2],hh[3]};
            *(f16x4*)&S.hfL[ktU][lqU][m][j0] = (f16x4){hl[0],hl[1],hl[2],hl[3]};
            { // stage gx_{t+1}, prefetch gx_{t+2}
#pragma unroll
                for (int j=0;j<6;j++) S.gxs[buf^1][tid+512*j] = gpre[j];
                int tn = tc + 2; if (tn > kTc-1) tn = kTc-1;
#pragma unroll
                for (int j=0;j<6;j++) gpre[j] = g32[(size_t)(mb*kTc + tn)*3072 + tid+512*j];
            }
            __syncthreads();
        }
        // persist h1 carry
        *(f32x4*)&h1state[(size_t)(b0+m)*kH + i0] = (f32x4){hreg[0],hreg[1],hreg[2],hreg[3]};
        // head on the final chunk
        if (e0 == kNCh-1){
            *(f32x4*)&S.gp[0][m][i0] = (f32x4){hreg[0],hreg[1],hreg[2],hreg[3]};
            __syncthreads();
#pragma unroll
            for (int e=0;e<4;e++){
                const float* wr = hw1 + (size_t)(i0+e)*kH;
                float s = hb1[i0+e];
                for (int k2=0;k2<kH;k2++) s = fmaf(wr[k2], S.gp[0][m][k2], s);
                S.gp[1][m][i0+e] = fmaxf(s, 0.f);
            }
            __syncthreads();
            if (tid < kMB){
                float s = hb2[0];
                for (int k2=0;k2<kH;k2++) s = fmaf(S.gp[1][tid][k2], hw2[k2], s);
                out[b0 + tid] = s;
            }
        }
    }
}

extern "C" void kernel_launch(void* const* d_in, const int* in_sizes, int n_in,
                              void* d_out, int out_size, void* d_ws, size_t ws_size,
                              hipStream_t stream)
{
    const float* x     = (const float*)d_in[0];
    const int*   tick  = (const int*)d_in[1];
    const float* embed = (const float*)d_in[2];
    const float* Wih0  = (const float*)d_in[3];
    const float* Whh0  = (const float*)d_in[4];
    const float* bih0  = (const float*)d_in[5];
    const float* bhh0  = (const float*)d_in[6];
    const float* Wih1  = (const float*)d_in[7];
    const float* Whh1  = (const float*)d_in[8];
    const float* bih1  = (const float*)d_in[9];
    const float* bhh1  = (const float*)d_in[10];
    const float* hw1   = (const float*)d_in[11];
    const float* hb1   = (const float*)d_in[12];
    const float* hw2   = (const float*)d_in[13];
    const float* hb2   = (const float*)d_in[14];
    float* out = (float*)d_out;

    // ws: h0seq 2 chunk bufs (32MB) | gx1 2 chunk bufs (48MB) | h1 carry (0.5MB)
    unsigned* h0seq = (unsigned*)d_ws;
    _Float16* gx1   = (_Float16*)((char*)d_ws + 2*kH0Str*sizeof(unsigned));
    float*  h1state = (float*)((char*)gx1 + 2*kGxStr*sizeof(_Float16));

    // 3-stage chunk pipeline: launch c runs l0(c) + gemm(c-1) + l1(c-2)
    for (int c = 0; c <= kNCh + 1; c++){
        rnn_fused<<<256, 512, 0, stream>>>(x, tick, embed,
            Wih0, Whh0, bih0, bhh0, Wih1, bih1, Whh1, bhh1,
            hw1, hb1, hw2, hb2, h0seq, gx1, h1state, out, c);
    }
}

// Round 6
// 1225.705 us; speedup vs baseline: 5.4732x; 1.1124x over previous
//
#include <hip/hip_runtime.h>

// Problem constants
constexpr int kB  = 1024;
constexpr int kT  = 512;
constexpr int kF  = 32;
constexpr int kE  = 16;
constexpr int kH  = 128;
constexpr int kMB = 16;             // batches per block (MFMA M)
constexpr int kNMB = kB / kMB;      // 64 batch tiles
constexpr int kTc = 32;             // chunk length
constexpr int kNCh = kT / kTc;      // 16 chunks
constexpr int kTg = kTc / 2;        // t-steps per GEMM block
constexpr size_t kH0Str = (size_t)kB * kTc * kH;     // u32 per h0 chunk buffer
constexpr size_t kSlots = (size_t)kNMB * kTc * 512;  // gx lane-slots per chunk

typedef __attribute__((ext_vector_type(8))) _Float16 f16x8;
typedef __attribute__((ext_vector_type(4))) _Float16 f16x4;
typedef __attribute__((ext_vector_type(4))) float    f32x4;

#define MFMA16(a,b,c) __builtin_amdgcn_mfma_f32_16x16x32_f16(a,b,c,0,0,0)

__device__ __forceinline__ float sigm_hw(float x){
    float e = __builtin_amdgcn_exp2f(-1.442695041f * x);
    return __builtin_amdgcn_rcpf(1.0f + e);
}
__device__ __forceinline__ float tanh_hw(float x){
    float e = __builtin_amdgcn_exp2f(-2.885390082f * x);
    return fmaf(2.0f, __builtin_amdgcn_rcpf(1.0f + e), -1.0f);
}
__device__ __forceinline__ void splitF(float v, _Float16 &hi, _Float16 &lo){
    hi = (_Float16)v;
    lo = (_Float16)(v - (float)hi);
}
__device__ __forceinline__ f16x8 loadW8(const float* __restrict__ p){
    f16x8 r;
#pragma unroll
    for (int j=0;j<8;j++) r[j] = (_Float16)p[j];
    return r;
}
__device__ __forceinline__ unsigned short f2u(_Float16 h){ return __builtin_bit_cast(unsigned short, h); }
__device__ __forceinline__ _Float16 u2f(unsigned short u){ return __builtin_bit_cast(_Float16, u); }
__device__ __forceinline__ unsigned pack2(float a, float b){
    return (unsigned)f2u((_Float16)a) | ((unsigned)f2u((_Float16)b) << 16);
}

// LDS: h planes row-major [m][k] (136 = 128 + 8 pad: 272B row stride keeps the
// 16-lane b128 read phases 2-way (free) and writes 4-way (cheap b16s)).
// Double buffered: step reads buf, writes nb=buf^1, ONE barrier per step.
struct SRec {
    alignas(16) _Float16 hH[2][16][136];
    alignas(16) _Float16 hL[2][16][136];
    alignas(16) _Float16 xHp[2][16][40];   // 40 = 32 + 8 pad (bank rotate)
    alignas(16) _Float16 xLp[2][16][40];
    alignas(16) float hf[16][132];         // head scratch
    alignas(16) float hf2[16][132];
};
struct SGem {
    alignas(16) _Float16 aH[2][16][136];
    alignas(16) _Float16 aL[2][16][136];
};
union SU { SRec r; SGem g; };

// ---------------------------------------------------------------------------
// 256 blocks x 512 threads, 3 pipeline roles per launch:
//   blocks   0..63 : layer-0 GRU chunk c
//   blocks 64..191 : gx1 GEMM for chunk c-1 (2 blocks per batch tile)
//   blocks 192..255: layer-1 GRU chunk c-2 (+head on last)
// In-lane gate update: wave w's lane (lq,lm), reg q owns element
// (m=lq*4+q, i=16w+lm) in ALL of r/z/n accumulators simultaneously (MFMA C
// layout), so sigmoid/tanh/state-update happen in-register; LDS only carries
// h_new -> A-fragment redistribution (8 b16 writes, 8 b128 reads, 1 barrier).
// ---------------------------------------------------------------------------
__attribute__((amdgpu_waves_per_eu(2, 2)))
__global__ void __launch_bounds__(512) rnn_fused(
    const float* __restrict__ x, const int* __restrict__ tick,
    const float* __restrict__ embed,
    const float* __restrict__ Wih0, const float* __restrict__ Whh0,
    const float* __restrict__ bih0, const float* __restrict__ bhh0,
    const float* __restrict__ Wih1, const float* __restrict__ bih1,
    const float* __restrict__ Whh1, const float* __restrict__ bhh1,
    const float* __restrict__ hw1, const float* __restrict__ hb1,
    const float* __restrict__ hw2, const float* __restrict__ hb2,
    unsigned* __restrict__ h0seq, unsigned* __restrict__ gxA,
    unsigned* __restrict__ gxB, float* __restrict__ h1state,
    float* __restrict__ out, int c)
{
    __shared__ SU sm;
    const int tid = threadIdx.x;
    const int w = tid >> 6, l = tid & 63, lm = l & 15, lq = l >> 4;
    const int i = 16*w + lm;                    // owned gate/hidden column
    const int cls[3] = { i, 128 + i, 256 + i }; // r/z/n weight rows

    if (blockIdx.x < 64) {
        // ================= layer-0 recurrence, chunk c =================
        if (c >= kNCh) return;
        SRec &S = sm.r;
        const int mb = blockIdx.x, b0 = mb * kMB;
        unsigned* h0w = h0seq + (size_t)(c & 1) * kH0Str;

        f16x8 wv[3][4], xw[3];
#pragma unroll
        for (int T=0; T<3; T++){
#pragma unroll
            for (int kt=0; kt<4; kt++)
                wv[T][kt] = loadW8(Whh0 + (size_t)cls[T]*kH + kt*32 + lq*8);
            xw[T] = loadW8(Wih0 + (size_t)cls[T]*48 + lq*8);
        }
        // acc inits: biases + (emb @ Wih0[:,32:48]) folded per (q, gate)
        float rIni[4], zIni[4], nxIni[4], nhIni;
        {
            float br = bih0[cls[0]] + bhh0[cls[0]];
            float bz = bih0[cls[1]] + bhh0[cls[1]];
            float bn = bih0[cls[2]];
            nhIni = bhh0[cls[2]];
            const float* w0 = Wih0 + (size_t)cls[0]*48 + 32;
            const float* w1 = Wih0 + (size_t)cls[1]*48 + 32;
            const float* w2 = Wih0 + (size_t)cls[2]*48 + 32;
#pragma unroll
            for (int q=0; q<4; q++){
                const float* ep = embed + (size_t)tick[b0 + lq*4 + q] * kE;
                float s0=0.f, s1=0.f, s2=0.f;
#pragma unroll
                for (int e=0; e<kE; e++){
                    float ev = ep[e];
                    s0 = fmaf(ev, w0[e], s0);
                    s1 = fmaf(ev, w1[e], s1);
                    s2 = fmaf(ev, w2[e], s2);
                }
                rIni[q]=br+s0; zIni[q]=bz+s1; nxIni[q]=bn+s2;
            }
        }
        // state init via ownership (covers all 16x128 exactly)
        float hreg[4];
        if (c == 0){
#pragma unroll
            for (int q=0;q<4;q++){
                hreg[q]=0.f;
                S.hH[0][lq*4+q][i]=(_Float16)0.f;
                S.hL[0][lq*4+q][i]=(_Float16)0.f;
            }
        } else {
            const unsigned* h0p = h0seq + (size_t)((c-1) & 1) * kH0Str;
#pragma unroll
            for (int q=0;q<4;q++){
                unsigned u = h0p[((size_t)(mb*kTc + kTc-1)*16 + lq*4+q)*kH + i];
                _Float16 hh = u2f((unsigned short)(u>>16)), hl = u2f((unsigned short)u);
                hreg[q] = (float)hh + (float)hl;
                S.hH[0][lq*4+q][i]=hh; S.hL[0][lq*4+q][i]=hl;
            }
        }
        // x staging role: thread owns (xm, xk); prefetch 1 step ahead
        const int xm = tid >> 5, xk = tid & 31;
        const size_t xbase = (size_t)(b0+xm)*kT*kF + xk;
        {
            _Float16 a2,b2; splitF(x[xbase + (size_t)(c*kTc)*kF], a2, b2);
            S.xHp[0][xm][xk]=a2; S.xLp[0][xm][xk]=b2;
        }
        int t1 = c*kTc + 1; if (t1 > kT-1) t1 = kT-1;
        float xnext = x[xbase + (size_t)t1*kF];
        __syncthreads();

        int buf = 0;
        for (int tc=0; tc<kTc; tc++){
            const int nb = buf ^ 1;
            f16x8 aHf[4], aLf[4];
#pragma unroll
            for (int kt=0;kt<4;kt++){
                aHf[kt] = *(const f16x8*)&S.hH[buf][lm][kt*32 + lq*8];
                aLf[kt] = *(const f16x8*)&S.hL[buf][lm][kt*32 + lq*8];
            }
            f16x8 xvH = *(const f16x8*)&S.xHp[buf][lm][lq*8];
            f16x8 xvL = *(const f16x8*)&S.xLp[buf][lm][lq*8];
            f32x4 aR ={rIni[0],rIni[1],rIni[2],rIni[3]};
            f32x4 aZ ={zIni[0],zIni[1],zIni[2],zIni[3]};
            f32x4 aNX={nxIni[0],nxIni[1],nxIni[2],nxIni[3]};
            f32x4 aNH={nhIni,nhIni,nhIni,nhIni};
#pragma unroll
            for (int kt=0;kt<4;kt++){
                aR =MFMA16(aHf[kt],wv[0][kt],aR);  aR =MFMA16(aLf[kt],wv[0][kt],aR);
                aZ =MFMA16(aHf[kt],wv[1][kt],aZ);  aZ =MFMA16(aLf[kt],wv[1][kt],aZ);
                aNH=MFMA16(aHf[kt],wv[2][kt],aNH); aNH=MFMA16(aLf[kt],wv[2][kt],aNH);
            }
            aR =MFMA16(xvH,xw[0],aR);  aR =MFMA16(xvL,xw[0],aR);
            aZ =MFMA16(xvH,xw[1],aZ);  aZ =MFMA16(xvL,xw[1],aZ);
            aNX=MFMA16(xvH,xw[2],aNX); aNX=MFMA16(xvL,xw[2],aNX);
            // in-lane gate + state update (MFMA C regs stay local)
            unsigned pk[4];
#pragma unroll
            for (int q=0;q<4;q++){
                float r = sigm_hw(aR[q]);
                float z = sigm_hw(aZ[q]);
                float n = tanh_hw(fmaf(r, aNH[q], aNX[q]));
                float h = fmaf(z, hreg[q]-n, n);
                hreg[q] = h;
                _Float16 hh,hl; splitF(h,hh,hl);
                S.hH[nb][lq*4+q][i]=hh;
                S.hL[nb][lq*4+q][i]=hl;
                pk[q] = ((unsigned)f2u(hh)<<16) | f2u(hl);
            }
#pragma unroll
            for (int q=0;q<4;q++)
                h0w[((size_t)(mb*kTc + tc)*16 + lq*4+q)*kH + i] = pk[q];
            { // stage x_{t+1}, prefetch x_{t+2}
                _Float16 a2,b2; splitF(xnext,a2,b2);
                S.xHp[nb][xm][xk]=a2; S.xLp[nb][xm][xk]=b2;
                int tn = c*kTc + tc + 2; if (tn > kT-1) tn = kT-1;
                xnext = x[xbase + (size_t)tn*kF];
            }
            __syncthreads();
            buf = nb;
        }
    } else if (blockIdx.x < 192) {
        // ============ gx1 GEMM for chunk g=c-1 (non-recurrent) ============
        const int g = c - 1;
        if (g < 0 || g >= kNCh) return;
        SGem &S = sm.g;
        const int bid = blockIdx.x - 64;
        const int mb = bid >> 1, t0 = (bid & 1) * kTg;
        const unsigned* h0r = h0seq + (size_t)(g & 1) * kH0Str;
        unsigned* gA = gxA + (size_t)(g & 1) * kSlots * 4;
        unsigned* gB = gxB + (size_t)(g & 1) * kSlots * 2;

        f16x8 wv[3][4]; float bI[3];
#pragma unroll
        for (int T=0; T<3; T++){
#pragma unroll
            for (int kt=0; kt<4; kt++)
                wv[T][kt] = loadW8(Wih1 + (size_t)cls[T]*kH + kt*32 + lq*8);
            bI[T] = bih1[cls[T]];
        }
        const int sr = tid >> 5, sq = tid & 31;   // staging role: row, u32-quad
        auto ld = [&](int t){
            return *(const uint4*)(h0r + ((size_t)(mb*kTc + t)*16 + sr)*kH + 4*sq);
        };
        auto stage = [&](int bf, uint4 u){
            f16x4 vh = { u2f((unsigned short)(u.x>>16)), u2f((unsigned short)(u.y>>16)),
                         u2f((unsigned short)(u.z>>16)), u2f((unsigned short)(u.w>>16)) };
            f16x4 vl = { u2f((unsigned short)u.x), u2f((unsigned short)u.y),
                         u2f((unsigned short)u.z), u2f((unsigned short)u.w) };
            *(f16x4*)&S.aH[bf][sr][4*sq] = vh;
            *(f16x4*)&S.aL[bf][sr][4*sq] = vl;
        };
        stage(0, ld(t0));
        uint4 nxt = ld(t0 + 1);
        __syncthreads();
        for (int tt=0; tt<kTg; tt++){
            const int t = t0 + tt, bf = tt & 1;
            f16x8 fH[4], fL[4];
#pragma unroll
            for (int kt=0;kt<4;kt++){
                fH[kt] = *(const f16x8*)&S.aH[bf][lm][kt*32 + lq*8];
                fL[kt] = *(const f16x8*)&S.aL[bf][lm][kt*32 + lq*8];
            }
            if (tt+1 < kTg) stage(bf^1, nxt);
            if (tt+2 < kTg) nxt = ld(t0 + tt + 2);
            f32x4 aR = {bI[0],bI[0],bI[0],bI[0]};
            f32x4 aZ = {bI[1],bI[1],bI[1],bI[1]};
            f32x4 aN = {bI[2],bI[2],bI[2],bI[2]};
#pragma unroll
            for (int kt=0;kt<4;kt++){
                aR=MFMA16(fH[kt],wv[0][kt],aR); aR=MFMA16(fL[kt],wv[0][kt],aR);
                aZ=MFMA16(fH[kt],wv[1][kt],aZ); aZ=MFMA16(fL[kt],wv[1][kt],aZ);
                aN=MFMA16(fH[kt],wv[2][kt],aN); aN=MFMA16(fL[kt],wv[2][kt],aN);
            }
            // store per-consumer-lane packed: l1 lane tid reads exactly this
            const size_t slot = ((size_t)mb*kTc + t)*512 + tid;
            *(uint4*)(gA + slot*4) = make_uint4(pack2(aR[0],aR[1]), pack2(aR[2],aR[3]),
                                                pack2(aZ[0],aZ[1]), pack2(aZ[2],aZ[3]));
            *(uint2*)(gB + slot*2) = make_uint2(pack2(aN[0],aN[1]), pack2(aN[2],aN[3]));
            __syncthreads();
        }
    } else {
        // ================= layer-1 recurrence, chunk e0=c-2 =================
        const int e0 = c - 2;
        if (e0 < 0 || e0 >= kNCh) return;
        SRec &S = sm.r;
        const int mb = blockIdx.x - 192, b0 = mb * kMB;
        const unsigned* gA = gxA + (size_t)(e0 & 1) * kSlots * 4;
        const unsigned* gB = gxB + (size_t)(e0 & 1) * kSlots * 2;

        f16x8 wv[3][4];
#pragma unroll
        for (int T=0; T<3; T++)
#pragma unroll
            for (int kt=0; kt<4; kt++)
                wv[T][kt] = loadW8(Whh1 + (size_t)cls[T]*kH + kt*32 + lq*8);
        const float br = bhh1[cls[0]], bz = bhh1[cls[1]], bn = bhh1[cls[2]];

        float hreg[4];
        if (e0 == 0){
#pragma unroll
            for (int q=0;q<4;q++){
                hreg[q]=0.f;
                S.hH[0][lq*4+q][i]=(_Float16)0.f;
                S.hL[0][lq*4+q][i]=(_Float16)0.f;
            }
        } else {
#pragma unroll
            for (int q=0;q<4;q++){
                float h = h1state[(size_t)(b0 + lq*4+q)*kH + i];
                hreg[q]=h;
                _Float16 hh,hl; splitF(h,hh,hl);
                S.hH[0][lq*4+q][i]=hh; S.hL[0][lq*4+q][i]=hl;
            }
        }
        // gx stream straight into registers, prefetched one step ahead
        const size_t base = (size_t)mb*kTc*512 + tid;
        uint4 g4c = *(const uint4*)(gA + base*4);
        uint2 g2c = *(const uint2*)(gB + base*2);
        uint4 g4n = *(const uint4*)(gA + (base + 512)*4);
        uint2 g2n = *(const uint2*)(gB + (base + 512)*2);
        __syncthreads();

        int buf = 0;
        for (int tc=0; tc<kTc; tc++){
            const int nb = buf ^ 1;
            f16x8 aHf[4], aLf[4];
#pragma unroll
            for (int kt=0;kt<4;kt++){
                aHf[kt] = *(const f16x8*)&S.hH[buf][lm][kt*32 + lq*8];
                aLf[kt] = *(const f16x8*)&S.hL[buf][lm][kt*32 + lq*8];
            }
            f32x4 aR={br,br,br,br}, aZ={bz,bz,bz,bz}, aNH={bn,bn,bn,bn};
#pragma unroll
            for (int kt=0;kt<4;kt++){
                aR =MFMA16(aHf[kt],wv[0][kt],aR);  aR =MFMA16(aLf[kt],wv[0][kt],aR);
                aZ =MFMA16(aHf[kt],wv[1][kt],aZ);  aZ =MFMA16(aLf[kt],wv[1][kt],aZ);
                aNH=MFMA16(aHf[kt],wv[2][kt],aNH); aNH=MFMA16(aLf[kt],wv[2][kt],aNH);
            }
            const float rx[4] = { (float)u2f((unsigned short)g4c.x), (float)u2f((unsigned short)(g4c.x>>16)),
                                  (float)u2f((unsigned short)g4c.y), (float)u2f((unsigned short)(g4c.y>>16)) };
            const float zx[4] = { (float)u2f((unsigned short)g4c.z), (float)u2f((unsigned short)(g4c.z>>16)),
                                  (float)u2f((unsigned short)g4c.w), (float)u2f((unsigned short)(g4c.w>>16)) };
            const float nx[4] = { (float)u2f((unsigned short)g2c.x), (float)u2f((unsigned short)(g2c.x>>16)),
                                  (float)u2f((unsigned short)g2c.y), (float)u2f((unsigned short)(g2c.y>>16)) };
#pragma unroll
            for (int q=0;q<4;q++){
                float r = sigm_hw(aR[q] + rx[q]);
                float z = sigm_hw(aZ[q] + zx[q]);
                float n = tanh_hw(fmaf(r, aNH[q], nx[q]));
                float h = fmaf(z, hreg[q]-n, n);
                hreg[q] = h;
                _Float16 hh,hl; splitF(h,hh,hl);
                S.hH[nb][lq*4+q][i]=hh;
                S.hL[nb][lq*4+q][i]=hl;
            }
            g4c = g4n; g2c = g2n;
            int tn = tc + 2; if (tn > kTc-1) tn = kTc-1;
            g4n = *(const uint4*)(gA + (base + (size_t)tn*512)*4);
            g2n = *(const uint2*)(gB + (base + (size_t)tn*512)*2);
            __syncthreads();
            buf = nb;
        }
#pragma unroll
        for (int q=0;q<4;q++)
            h1state[(size_t)(b0 + lq*4+q)*kH + i] = hreg[q];
        if (e0 == kNCh-1){
            // head: hid = relu(h1 @ hw1^T + hb1); y = hid @ hw2^T + hb2
#pragma unroll
            for (int q=0;q<4;q++) S.hf[lq*4+q][i] = hreg[q];
            __syncthreads();
            const int hm = tid >> 5, i0 = (tid & 31) * 4;
#pragma unroll
            for (int e=0;e<4;e++){
                const float* wr = hw1 + (size_t)(i0+e)*kH;
                float s = hb1[i0+e];
                for (int k2=0;k2<kH;k2++) s = fmaf(wr[k2], S.hf[hm][k2], s);
                S.hf2[hm][i0+e] = fmaxf(s, 0.f);
            }
            __syncthreads();
            if (tid < kMB){
                float s = hb2[0];
                for (int k2=0;k2<kH;k2++) s = fmaf(S.hf2[tid][k2], hw2[k2], s);
                out[b0 + tid] = s;
            }
        }
    }
}

extern "C" void kernel_launch(void* const* d_in, const int* in_sizes, int n_in,
                              void* d_out, int out_size, void* d_ws, size_t ws_size,
                              hipStream_t stream)
{
    const float* x     = (const float*)d_in[0];
    const int*   tick  = (const int*)d_in[1];
    const float* embed = (const float*)d_in[2];
    const float* Wih0  = (const float*)d_in[3];
    const float* Whh0  = (const float*)d_in[4];
    const float* bih0  = (const float*)d_in[5];
    const float* bhh0  = (const float*)d_in[6];
    const float* Wih1  = (const float*)d_in[7];
    const float* Whh1  = (const float*)d_in[8];
    const float* bih1  = (const float*)d_in[9];
    const float* bhh1  = (const float*)d_in[10];
    const float* hw1   = (const float*)d_in[11];
    const float* hb1   = (const float*)d_in[12];
    const float* hw2   = (const float*)d_in[13];
    const float* hb2   = (const float*)d_in[14];
    float* out = (float*)d_out;

    // ws: h0seq 2x16.8MB | gxA 2x16.8MB | gxB 2x8.4MB | h1state 0.5MB ~ 84.5MB
    unsigned* h0seq = (unsigned*)d_ws;
    unsigned* gxA   = h0seq + 2*kH0Str;
    unsigned* gxB   = gxA + 2*kSlots*4;
    float*  h1state = (float*)(gxB + 2*kSlots*2);

    for (int c = 0; c <= kNCh + 1; c++){
        rnn_fused<<<256, 512, 0, stream>>>(x, tick, embed,
            Wih0, Whh0, bih0, bhh0, Wih1, bih1, Whh1, bhh1,
            hw1, hb1, hw2, hb2, h0seq, gxA, gxB, h1state, out, c);
    }
}